// Round 6
// baseline (243.594 us; speedup 1.0000x reference)
//
#include <hip/hip_runtime.h>
#include <math.h>

#define NC 80
#define TOPKK 10
#define EPSF 1e-9f
#define IOU_EPSF 1e-7f
#define NA 8400
#define NGMAX 64
#define CH 128
#define NCH ((NA + CH - 1) / CH)   // 66

typedef float f4nt __attribute__((ext_vector_type(4)));

// IoU exactly as reference: inter/(a1+a2-inter+eps)
__device__ __forceinline__ float iou_xyxy(float px0, float py0, float px1, float py1,
                                          float parea,
                                          float gx0, float gy0, float gx1, float gy1,
                                          float garea) {
    float iw = fmaxf(fminf(px1, gx1) - fmaxf(px0, gx0), 0.0f);
    float ih = fmaxf(fminf(py1, gy1) - fmaxf(py0, gy0), 0.0f);
    float inter = iw * ih;
    return inter / (parea + garea - inter + IOU_EPSF);
}

__device__ __forceinline__ float align_metric(float s, float ov) {
    float ov2 = ov * ov;
    return sqrtf(s) * (ov2 * ov2 * ov2);
}

// ---------------- two-phase top-k (needs ~13 MB ws) ----------------

// Phase 1: block per (b, chunk of 128 anchors). Stage scores/bboxes/anchors
// into LDS coalesced; 4 threads per g scan the chunk keeping register top-10;
// 4-way merge per g; write sorted top-10 keys per (b,chunk,g) to ws.
// Key = (float_bits(v)<<32) | ~idx : strict total order == (v desc, idx asc).
__global__ __launch_bounds__(256) void topk_phase1(
    const float* __restrict__ pd_scores, const float* __restrict__ pd_bboxes,
    const float* __restrict__ anc, const int* __restrict__ gt_labels,
    const float* __restrict__ gt_bboxes, const int* __restrict__ mask_gt,
    unsigned long long* __restrict__ cand, int ng)
{
    __shared__ union {
        float sc[CH * NC];                        // 40 KB score slab
        unsigned long long mk[NGMAX * 4 * TOPKK]; // 20 KB merge buffer (aliased)
    } U;
    __shared__ float4 sbb[CH];
    __shared__ float2 sanc[CH];
    __shared__ float4 sgt[NGMAX];
    __shared__ int    slab[NGMAX];
    __shared__ int    svalid[NGMAX];

    int b  = blockIdx.x / NCH;
    int c  = blockIdx.x - b * NCH;
    int a0 = c * CH;
    int rows = NA - a0; if (rows > CH) rows = CH;

    for (int g = threadIdx.x; g < NGMAX; g += 256) {
        if (g < ng) {
            sgt[g]    = ((const float4*)gt_bboxes)[b * ng + g];
            slab[g]   = gt_labels[b * ng + g];
            svalid[g] = mask_gt[b * ng + g];
        } else {
            sgt[g] = make_float4(0, 0, 0, 0); slab[g] = 0; svalid[g] = 0;
        }
    }
    for (int i = threadIdx.x; i < rows; i += 256) {
        sbb[i]  = ((const float4*)pd_bboxes)[(long)b * NA + a0 + i];
        sanc[i] = ((const float2*)anc)[a0 + i];
    }
    {
        const float4* src = (const float4*)(pd_scores + ((long)b * NA + a0) * NC);
        float4* dst = (float4*)U.sc;
        int n4 = rows * (NC / 4);
        for (int i = threadIdx.x; i < n4; i += 256) dst[i] = src[i];
    }
    __syncthreads();

    int g   = threadIdx.x & 63;
    int sub = threadIdx.x >> 6;          // wave-uniform

    float lv[TOPKK]; int li[TOPKK];
#pragma unroll
    for (int j = 0; j < TOPKK; ++j) { lv[j] = -1.0f; li[j] = -1; }

    if (svalid[g] != 0) {
        float4 gb = sgt[g];
        float garea = (gb.z - gb.x) * (gb.w - gb.y);
        int lab = slab[g];
        for (int al = sub; al < rows; al += 4) {   // idx ascending per thread
            float2 ap = sanc[al];
            float d0 = ap.x - gb.x, d1 = ap.y - gb.y, d2 = gb.z - ap.x, d3 = gb.w - ap.y;
            float dmin = fminf(fminf(d0, d1), fminf(d2, d3));
            float v = 0.0f;
            if (dmin > EPSF) {
                float4 pb = sbb[al];
                float parea = (pb.z - pb.x) * (pb.w - pb.y);
                float ov = iou_xyxy(pb.x, pb.y, pb.z, pb.w, parea,
                                    gb.x, gb.y, gb.z, gb.w, garea);
                float s = U.sc[al * NC + lab];
                v = align_metric(s, ov);
            }
            if (v > lv[TOPKK - 1]) {   // branchless sorted insert, ties keep earlier
                int a = a0 + al;
                float nv[TOPKK]; int ni[TOPKK];
#pragma unroll
                for (int j = 0; j < TOPKK; ++j) {
                    bool keep = (lv[j] >= v);
                    bool atp  = (j == 0) ? !keep : (!keep && (lv[j - 1] >= v));
                    nv[j] = keep ? lv[j] : (atp ? v : lv[j - 1]);
                    ni[j] = keep ? li[j] : (atp ? a : li[j - 1]);
                }
#pragma unroll
                for (int j = 0; j < TOPKK; ++j) { lv[j] = nv[j]; li[j] = ni[j]; }
            }
        }
    }

    __syncthreads();   // all score reads done before aliased mk writes
#pragma unroll
    for (int j = 0; j < TOPKK; ++j) {
        unsigned long long k = (lv[j] < 0.0f) ? 0ull
            : (((unsigned long long)__float_as_uint(lv[j]) << 32)
               | (unsigned)(~(unsigned)li[j]));
        U.mk[(g * 4 + sub) * TOPKK + j] = k;
    }
    __syncthreads();

    if (threadIdx.x < 64) {
        int gg = threadIdx.x;
        const unsigned long long* L = &U.mk[gg * 4 * TOPKK];
        unsigned long long* outp = &cand[(((long)b * NCH + c) * 64 + gg) * TOPKK];
        int p0 = 0, p1 = 0, p2 = 0, p3 = 0;
#pragma unroll
        for (int j = 0; j < TOPKK; ++j) {
            unsigned long long k0 = L[0 * TOPKK + p0], k1 = L[1 * TOPKK + p1];
            unsigned long long k2 = L[2 * TOPKK + p2], k3 = L[3 * TOPKK + p3];
            unsigned long long bk = k0; int bi = 0;
            if (k1 > bk) { bk = k1; bi = 1; }
            if (k2 > bk) { bk = k2; bi = 2; }
            if (k3 > bk) { bk = k3; bi = 3; }
            outp[j] = bk;
            if (bk != 0ull) {   // sentinel: don't advance (all further are 0)
                if (bi == 0) p0++; else if (bi == 1) p1++;
                else if (bi == 2) p2++; else p3++;
            }
        }
    }
}

// Phase 2: one wave per (b,g). Merge 66 chunk top-10 lists (2 chunks/lane ->
// per-lane top-10), then 10 butterfly max-extract rounds -> atomicOr bits.
__global__ __launch_bounds__(64) void topk_phase2(
    const unsigned long long* __restrict__ cand, const int* __restrict__ mask_gt,
    unsigned long long* __restrict__ bits, int ng)
{
    int b = blockIdx.x / ng;
    int g = blockIdx.x - b * ng;
    if (mask_gt[b * ng + g] == 0) return;
    int lane = threadIdx.x;

    unsigned long long A[TOPKK], B[TOPKK], M[TOPKK];
    {
        const unsigned long long* p = &cand[(((long)b * NCH + lane) * 64 + g) * TOPKK];
#pragma unroll
        for (int j = 0; j < TOPKK; ++j) A[j] = p[j];
    }
    int c2 = lane + 64;
    if (c2 < NCH) {
        const unsigned long long* p = &cand[(((long)b * NCH + c2) * 64 + g) * TOPKK];
#pragma unroll
        for (int j = 0; j < TOPKK; ++j) B[j] = p[j];
    } else {
#pragma unroll
        for (int j = 0; j < TOPKK; ++j) B[j] = 0ull;
    }
    {
        int pa = 0, pb = 0;
#pragma unroll
        for (int j = 0; j < TOPKK; ++j) {
            unsigned long long ka = A[pa], kb = B[pb];
            if (ka >= kb) { M[j] = ka; if (ka != 0ull) pa++; }
            else          { M[j] = kb; pb++; }
        }
    }

    int pos = 0;
    long bbase = (long)b * NA;
    for (int it = 0; it < TOPKK; ++it) {
        unsigned long long myk = (pos < TOPKK) ? M[pos] : 0ull;
        unsigned long long k = myk;
#pragma unroll
        for (int off = 32; off > 0; off >>= 1) {
            unsigned long long o = __shfl_xor(k, off, 64);
            k = (o > k) ? o : k;
        }
        if (k == 0ull) break;          // uniform across the wave
        if (myk == k) {                // unique owner
            unsigned idx = ~(unsigned)k;
            atomicOr(&bits[bbase + idx], 1ull << g);
            pos++;
        }
    }
}

// ---------------- fallback single-kernel top-k (R4, ~2.15 MB ws) ----------------

__global__ __launch_bounds__(256) void topk_kernel(
    const float* __restrict__ pd_scores, const float* __restrict__ pd_bboxes,
    const float* __restrict__ anc, const int* __restrict__ gt_labels,
    const float* __restrict__ gt_bboxes, const int* __restrict__ mask_gt,
    unsigned long long* __restrict__ bits, int ng, int swz)
{
    __shared__ unsigned long long wkey[2][4];

    int b, g;
    if (swz) {
        int x = blockIdx.x & 7;
        int j = blockIdx.x >> 3;
        b = x * swz + j / ng;
        g = j - (j / ng) * ng;
    } else {
        b = blockIdx.x / ng;
        g = blockIdx.x - b * ng;
    }
    if (mask_gt[b * ng + g] == 0) return;

    int lab = gt_labels[b * ng + g];
    const float4 gb = ((const float4*)gt_bboxes)[b * ng + g];
    float gx0 = gb.x, gy0 = gb.y, gx1 = gb.z, gy1 = gb.w;
    float garea = (gx1 - gx0) * (gy1 - gy0);

    const float* __restrict__ srow = pd_scores + ((long)b * NA) * NC + lab;
    const float4* __restrict__ pbb = (const float4*)(pd_bboxes + (long)b * NA * 4);

    float lv[TOPKK]; int li[TOPKK];
#pragma unroll
    for (int j = 0; j < TOPKK; ++j) { lv[j] = -1.0f; li[j] = -1; }

    for (int a = threadIdx.x; a < NA; a += 256) {
        float ax = anc[a * 2 + 0];
        float ay = anc[a * 2 + 1];
        float d0 = ax - gx0, d1 = ay - gy0, d2 = gx1 - ax, d3 = gy1 - ay;
        float dmin = fminf(fminf(d0, d1), fminf(d2, d3));
        float v = 0.0f;
        if (dmin > EPSF) {
            float4 pb = pbb[a];
            float parea = (pb.z - pb.x) * (pb.w - pb.y);
            float ov = iou_xyxy(pb.x, pb.y, pb.z, pb.w, parea, gx0, gy0, gx1, gy1, garea);
            float s = srow[(long)a * NC];
            v = align_metric(s, ov);
        }
        if (v > lv[TOPKK - 1]) {
            float nv[TOPKK]; int ni[TOPKK];
#pragma unroll
            for (int j = 0; j < TOPKK; ++j) {
                bool keep = (lv[j] >= v);
                bool atp  = (j == 0) ? !keep : (!keep && (lv[j - 1] >= v));
                nv[j] = keep ? lv[j] : (atp ? v : lv[j - 1]);
                ni[j] = keep ? li[j] : (atp ? a : li[j - 1]);
            }
#pragma unroll
            for (int j = 0; j < TOPKK; ++j) { lv[j] = nv[j]; li[j] = ni[j]; }
        }
    }

    int lane = threadIdx.x & 63;
    int wid  = threadIdx.x >> 6;
    long bbase = (long)b * NA;

    for (int it = 0; it < TOPKK; ++it) {
        unsigned vb = __float_as_uint(lv[0]);
        unsigned long long myk = (lv[0] < 0.0f) ? 0ull
            : (((unsigned long long)vb << 32) | (unsigned)(~(unsigned)li[0]));

        unsigned long long k = myk;
#pragma unroll
        for (int off = 32; off > 0; off >>= 1) {
            unsigned long long o = __shfl_xor(k, off, 64);
            k = (o > k) ? o : k;
        }
        if (lane == 0) wkey[it & 1][wid] = k;
        __syncthreads();
        unsigned long long gk = wkey[it & 1][0];
        gk = (wkey[it & 1][1] > gk) ? wkey[it & 1][1] : gk;
        gk = (wkey[it & 1][2] > gk) ? wkey[it & 1][2] : gk;
        gk = (wkey[it & 1][3] > gk) ? wkey[it & 1][3] : gk;

        if (gk != 0ull && myk == gk) {
            atomicOr(&bits[bbase + li[0]], 1ull << g);
#pragma unroll
            for (int j = 0; j < TOPKK - 1; ++j) { lv[j] = lv[j + 1]; li[j] = li[j + 1]; }
            lv[TOPKK - 1] = -1.0f; li[TOPKK - 1] = -1;
        }
    }
}

// ---------------- fused assign + scores ----------------

__global__ __launch_bounds__(256) void assign_scores_kernel(
    const float* __restrict__ pd_scores, const float* __restrict__ pd_bboxes,
    const float* __restrict__ anc, const int* __restrict__ gt_labels,
    const float* __restrict__ gt_bboxes, const int* __restrict__ mask_gt,
    const unsigned long long* __restrict__ bits,
    float* __restrict__ out_labels, float* __restrict__ out_bboxes,
    float* __restrict__ out_scores, float* __restrict__ out_fg,
    float* __restrict__ out_tgt, int ng, int blocksPerB)
{
    __shared__ float4 sgt[NGMAX];
    __shared__ float  sarea[NGMAX];
    __shared__ int    slab[NGMAX];
    __shared__ int    svalid[NGMAX];
    __shared__ int    plab[256];
    __shared__ float  pt[256];

    int b  = blockIdx.x / blocksPerB;
    int a0 = (blockIdx.x - b * blocksPerB) * 256;
    int a  = a0 + threadIdx.x;

    for (int g = threadIdx.x; g < ng; g += 256) {
        float4 gb = ((const float4*)gt_bboxes)[b * ng + g];
        sgt[g] = gb;
        sarea[g] = (gb.z - gb.x) * (gb.w - gb.y);
        slab[g] = gt_labels[b * ng + g];
        svalid[g] = mask_gt[b * ng + g];
    }
    __syncthreads();

    bool alive = (a < NA);
    int labi0 = slab[0] < 0 ? 0 : slab[0];
    int labi = labi0; float t = 0.0f;

    if (alive) {
        long ba = (long)b * NA + a;
        unsigned long long w = bits[ba];
        if (w == 0ull) {
            // fg=0, tgt=argmax(zeros)=0: defaults, exact per reference algebra
            out_labels[ba] = (float)labi0;
            ((float4*)out_bboxes)[ba] = sgt[0];
            out_fg[ba]  = 0.0f;
            out_tgt[ba] = 0.0f;
        } else {
            float ax = anc[a * 2 + 0];
            float ay = anc[a * 2 + 1];
            float4 pb = ((const float4*)pd_bboxes)[ba];
            float parea = (pb.z - pb.x) * (pb.w - pb.y);
            const float* __restrict__ srow = pd_scores + ba * NC;

            int cnt = 0, pos_g = 0;
            float best_ov = 0.0f; int best_g = 0;
            float m_align = 0.0f, m_ov = 0.0f, t_raw = 0.0f;

            for (int g = 0; g < ng; ++g) {
                if (svalid[g] == 0) break;   // mask_gt is a prefix
                float4 gb = sgt[g];
                float d0 = ax - gb.x, d1 = ay - gb.y, d2 = gb.z - ax, d3 = gb.w - ay;
                float dmin = fminf(fminf(d0, d1), fminf(d2, d3));
                bool mask = (dmin > EPSF);
                float ov = 0.0f, al = 0.0f;
                if (mask) {
                    ov = iou_xyxy(pb.x, pb.y, pb.z, pb.w, parea,
                                  gb.x, gb.y, gb.z, gb.w, sarea[g]);
                    float s = srow[slab[g]];
                    al = align_metric(s, ov);
                }
                bool pos = mask && ((w >> g) & 1ull);
                if (pos) { if (cnt == 0) pos_g = g; cnt++; }
                if (ov > best_ov) { best_ov = ov; best_g = g; }  // first max wins
                m_align = fmaxf(m_align, al);
                m_ov    = fmaxf(m_ov, ov);
                t_raw   = fmaxf(t_raw, al * ov);
            }

            int fg  = (cnt > 0) ? 1 : 0;
            int tgt = (cnt > 1) ? best_g : ((cnt == 1) ? pos_g : 0);

            labi = slab[tgt]; if (labi < 0) labi = 0;
            out_labels[ba] = (float)labi;
            ((float4*)out_bboxes)[ba] = sgt[tgt];
            out_fg[ba]  = (float)fg;
            out_tgt[ba] = (float)tgt;

            if (fg) {
                float na_ = fmaxf(m_align, EPSF);
                float no_ = fmaxf(m_ov, EPSF);
                t = (t_raw / na_) / no_;
            }
        }
    }

    plab[threadIdx.x] = labi;
    pt[threadIdx.x]   = t;
    __syncthreads();

    int cnt_rows = NA - a0; if (cnt_rows > 256) cnt_rows = 256;
    int tot4 = cnt_rows * (NC / 4);
    f4nt* __restrict__ oslab = (f4nt*)(out_scores + ((long)b * NA + a0) * NC);
    for (int i = threadIdx.x; i < tot4; i += 256) {
        int al = i / (NC / 4);
        int cg = (i - al * (NC / 4)) * 4;
        int lab = plab[al];
        float tv = pt[al];
        f4nt o;
        o.x = (cg     == lab) ? tv : 0.0f;
        o.y = (cg + 1 == lab) ? tv : 0.0f;
        o.z = (cg + 2 == lab) ? tv : 0.0f;
        o.w = (cg + 3 == lab) ? tv : 0.0f;
        __builtin_nontemporal_store(o, &oslab[i]);
    }
}

extern "C" void kernel_launch(void* const* d_in, const int* in_sizes, int n_in,
                              void* d_out, int out_size, void* d_ws, size_t ws_size,
                              hipStream_t stream) {
    const float* pd_scores = (const float*)d_in[0];
    const float* pd_bboxes = (const float*)d_in[1];
    const float* anc       = (const float*)d_in[2];
    const int*   gt_labels = (const int*)d_in[3];
    const float* gt_bboxes = (const float*)d_in[4];
    const int*   mask_gt   = (const int*)d_in[5];

    int na = in_sizes[2] / 2;            // 8400
    int bs = in_sizes[0] / (na * NC);    // 32
    int ng = in_sizes[3] / bs;           // 64

    long nBA = (long)bs * na;
    float* out        = (float*)d_out;
    float* out_labels = out;                 // bs*na
    float* out_bboxes = out + nBA;           // bs*na*4
    float* out_scores = out + nBA * 5;       // bs*na*80
    float* out_fg     = out + nBA * 85;      // bs*na
    float* out_tgt    = out + nBA * 86;      // bs*na

    unsigned long long* bits = (unsigned long long*)d_ws;
    unsigned long long* cand = bits + nBA;

    size_t need = (size_t)nBA * 8 + (size_t)bs * NCH * 64 * TOPKK * 8;

    hipMemsetAsync(d_ws, 0, nBA * sizeof(unsigned long long), stream);

    if (ws_size >= need) {
        topk_phase1<<<bs * NCH, 256, 0, stream>>>(
            pd_scores, pd_bboxes, anc, gt_labels, gt_bboxes, mask_gt, cand, ng);
        topk_phase2<<<bs * ng, 64, 0, stream>>>(cand, mask_gt, bits, ng);
    } else {
        int swz = (bs % 8 == 0) ? (bs / 8) : 0;
        topk_kernel<<<bs * ng, 256, 0, stream>>>(
            pd_scores, pd_bboxes, anc, gt_labels, gt_bboxes, mask_gt, bits, ng, swz);
    }

    int bpb = (na + 255) / 256;
    assign_scores_kernel<<<bs * bpb, 256, 0, stream>>>(
        pd_scores, pd_bboxes, anc, gt_labels, gt_bboxes, mask_gt, bits,
        out_labels, out_bboxes, out_scores, out_fg, out_tgt, ng, bpb);
}

// Round 7
// 200.328 us; speedup vs baseline: 1.2160x; 1.2160x over previous
//
#include <hip/hip_runtime.h>
#include <math.h>

#define NC 80
#define TOPKK 10
#define EPSF 1e-9f
#define IOU_EPSF 1e-7f
#define NA 8400
#define NGMAX 64

typedef float f4nt __attribute__((ext_vector_type(4)));

// IoU exactly as reference: inter/(a1+a2-inter+eps)
__device__ __forceinline__ float iou_xyxy(float px0, float py0, float px1, float py1,
                                          float parea,
                                          float gx0, float gy0, float gx1, float gy1,
                                          float garea) {
    float iw = fmaxf(fminf(px1, gx1) - fmaxf(px0, gx0), 0.0f);
    float ih = fmaxf(fminf(py1, gy1) - fmaxf(py0, gy0), 0.0f);
    float inter = iw * ih;
    return inter / (parea + garea - inter + IOU_EPSF);
}

__device__ __forceinline__ float align_metric(float s, float ov) {
    float ov2 = ov * ov;
    return sqrtf(s) * (ov2 * ov2 * ov2);
}

// Top-k, rect-restricted: one 64-lane wave per (b,g); 4 waves per block; no LDS.
// Candidates = anchors inside a ±1-slack rectangle per grid level (8/16/32),
// exact dmin>EPS test per anchor. Per-lane sorted top-10 (positives only),
// 10 butterfly max-extract rounds with key (v_bits<<32)|~idx (= value desc,
// index asc — jax.lax.top_k order). If p<10 positives, lane 0 replicates the
// reference's zero-fill: lowest-index non-positive anchors get the bit
// (mask-false bits are inert downstream since pos = mask && bit).
__global__ __launch_bounds__(256) void topk_rect_kernel(
    const float* __restrict__ pd_scores, const float* __restrict__ pd_bboxes,
    const int* __restrict__ gt_labels, const float* __restrict__ gt_bboxes,
    const int* __restrict__ mask_gt,
    unsigned long long* __restrict__ bits, int ng, int total_bg)
{
    int lin = blockIdx.x * 4 + (threadIdx.x >> 6);
    if (lin >= total_bg) return;
    int b = lin / ng;
    int g = lin - b * ng;
    if (mask_gt[b * ng + g] == 0) return;   // wave-uniform exit
    int lane = threadIdx.x & 63;

    int lab = gt_labels[b * ng + g];
    float4 gb = ((const float4*)gt_bboxes)[b * ng + g];
    float garea = (gb.z - gb.x) * (gb.w - gb.y);
    const float* __restrict__ srow = pd_scores + ((long)b * NA) * NC + lab;
    const float4* __restrict__ pbb = (const float4*)(pd_bboxes + (long)b * NA * 4);

    // per-level candidate rectangles (superset; exact test inside loop)
    const int ls[3] = {8, 16, 32};
    const int ln[3] = {80, 40, 20};
    const int lb[3] = {0, 6400, 8000};
    int jlo[3], ilo[3], rw[3], cnt[3];
    int tot = 0;
#pragma unroll
    for (int l = 0; l < 3; ++l) {
        float s = (float)ls[l];
        int j0 = (int)floorf(gb.x / s - 0.5f) - 1; if (j0 < 0) j0 = 0;
        int j1 = (int)ceilf (gb.z / s - 0.5f) + 1; if (j1 > ln[l] - 1) j1 = ln[l] - 1;
        int i0 = (int)floorf(gb.y / s - 0.5f) - 1; if (i0 < 0) i0 = 0;
        int i1 = (int)ceilf (gb.w / s - 0.5f) + 1; if (i1 > ln[l] - 1) i1 = ln[l] - 1;
        int w = j1 - j0 + 1; if (w < 0) w = 0;
        int h = i1 - i0 + 1; if (h < 0) h = 0;
        jlo[l] = j0; ilo[l] = i0; rw[l] = w; cnt[l] = w * h; tot += cnt[l];
    }

    float lv[TOPKK]; int li[TOPKK];
#pragma unroll
    for (int j = 0; j < TOPKK; ++j) { lv[j] = -1.0f; li[j] = -1; }

    for (int t = lane; t < tot; t += 64) {   // t ascending => anchor idx ascending
        int l = 0, r = t;
        if (r >= cnt[0]) { r -= cnt[0]; l = 1; }
        if (l == 1 && r >= cnt[1]) { r -= cnt[1]; l = 2; }
        int i  = r / rw[l];
        int j  = r - i * rw[l];
        int ii = ilo[l] + i, jj = jlo[l] + j;
        int a  = lb[l] + ii * ln[l] + jj;
        float s  = (float)ls[l];
        float ax = (jj + 0.5f) * s, ay = (ii + 0.5f) * s;
        float d0 = ax - gb.x, d1 = ay - gb.y, d2 = gb.z - ax, d3 = gb.w - ay;
        float dmin = fminf(fminf(d0, d1), fminf(d2, d3));
        if (dmin > EPSF) {
            float4 pb = pbb[a];
            float parea = (pb.z - pb.x) * (pb.w - pb.y);
            float ov = iou_xyxy(pb.x, pb.y, pb.z, pb.w, parea,
                                gb.x, gb.y, gb.z, gb.w, garea);
            float sc = srow[(long)a * NC];
            float v = align_metric(sc, ov);
            if (v > 0.0f && v > lv[TOPKK - 1]) {   // positives only; sorted insert
                float nv[TOPKK]; int ni[TOPKK];
#pragma unroll
                for (int q = 0; q < TOPKK; ++q) {
                    bool keep = (lv[q] >= v);
                    bool atp  = (q == 0) ? !keep : (!keep && (lv[q - 1] >= v));
                    nv[q] = keep ? lv[q] : (atp ? v : lv[q - 1]);
                    ni[q] = keep ? li[q] : (atp ? a : li[q - 1]);
                }
#pragma unroll
                for (int q = 0; q < TOPKK; ++q) { lv[q] = nv[q]; li[q] = ni[q]; }
            }
        }
    }

    long bbase = (long)b * NA;
    int m = 0;
    for (int it = 0; it < TOPKK; ++it) {
        unsigned long long myk = (lv[0] > 0.0f)
            ? (((unsigned long long)__float_as_uint(lv[0]) << 32)
               | (unsigned)(~(unsigned)li[0]))
            : 0ull;
        unsigned long long k = myk;
#pragma unroll
        for (int off = 32; off > 0; off >>= 1) {
            unsigned long long o = __shfl_xor(k, off, 64);
            k = (o > k) ? o : k;
        }
        if (k == 0ull) break;     // all positives drained (wave-uniform)
        if (myk == k) {           // unique owner pops + records
            atomicOr(&bits[bbase + li[0]], 1ull << g);
#pragma unroll
            for (int q = 0; q < TOPKK - 1; ++q) { lv[q] = lv[q + 1]; li[q] = li[q + 1]; }
            lv[TOPKK - 1] = -1.0f; li[TOPKK - 1] = -1;
        }
        m++;
    }

    // zero-fill to 10 per jax.lax.top_k: lowest-index anchors whose column
    // value is 0 (recompute exactly; skip positives = already emitted).
    if (m < TOPKK && lane == 0) {
        int need = TOPKK - m;
        for (int a = 0; need > 0 && a < NA; ++a) {
            int l  = (a < 6400) ? 0 : ((a < 8000) ? 1 : 2);
            int rr = a - lb[l];
            int ii = rr / ln[l];
            int jj = rr - ii * ln[l];
            float s  = (float)ls[l];
            float ax = (jj + 0.5f) * s, ay = (ii + 0.5f) * s;
            float d0 = ax - gb.x, d1 = ay - gb.y, d2 = gb.z - ax, d3 = gb.w - ay;
            float dmin = fminf(fminf(d0, d1), fminf(d2, d3));
            bool positive = false;
            if (dmin > EPSF) {
                float4 pb = pbb[a];
                float parea = (pb.z - pb.x) * (pb.w - pb.y);
                float ov = iou_xyxy(pb.x, pb.y, pb.z, pb.w, parea,
                                    gb.x, gb.y, gb.z, gb.w, garea);
                float sc = srow[(long)a * NC];
                positive = (align_metric(sc, ov) > 0.0f);
            }
            if (!positive) {   // zero-valued entry: reference puts it in topk
                atomicOr(&bits[bbase + a], 1ull << g);  // inert if mask-false
                need--;
            }
        }
    }
}

// Fused assign + scores. w==0 fast path: fg=0, tgt=0 -> defaults, no g-loop.
__global__ __launch_bounds__(256) void assign_scores_kernel(
    const float* __restrict__ pd_scores, const float* __restrict__ pd_bboxes,
    const float* __restrict__ anc, const int* __restrict__ gt_labels,
    const float* __restrict__ gt_bboxes, const int* __restrict__ mask_gt,
    const unsigned long long* __restrict__ bits,
    float* __restrict__ out_labels, float* __restrict__ out_bboxes,
    float* __restrict__ out_scores, float* __restrict__ out_fg,
    float* __restrict__ out_tgt, int ng, int blocksPerB)
{
    __shared__ float4 sgt[NGMAX];
    __shared__ float  sarea[NGMAX];
    __shared__ int    slab[NGMAX];
    __shared__ int    svalid[NGMAX];
    __shared__ int    plab[256];
    __shared__ float  pt[256];

    int b  = blockIdx.x / blocksPerB;
    int a0 = (blockIdx.x - b * blocksPerB) * 256;
    int a  = a0 + threadIdx.x;

    for (int g = threadIdx.x; g < ng; g += 256) {
        float4 gb = ((const float4*)gt_bboxes)[b * ng + g];
        sgt[g] = gb;
        sarea[g] = (gb.z - gb.x) * (gb.w - gb.y);
        slab[g] = gt_labels[b * ng + g];
        svalid[g] = mask_gt[b * ng + g];
    }
    __syncthreads();

    bool alive = (a < NA);
    int labi0 = slab[0] < 0 ? 0 : slab[0];
    int labi = labi0; float t = 0.0f;

    if (alive) {
        long ba = (long)b * NA + a;
        unsigned long long w = bits[ba];
        if (w == 0ull) {
            // fg=0, tgt=argmax(zeros)=0: defaults, exact per reference algebra
            out_labels[ba] = (float)labi0;
            ((float4*)out_bboxes)[ba] = sgt[0];
            out_fg[ba]  = 0.0f;
            out_tgt[ba] = 0.0f;
        } else {
            float ax = anc[a * 2 + 0];
            float ay = anc[a * 2 + 1];
            float4 pb = ((const float4*)pd_bboxes)[ba];
            float parea = (pb.z - pb.x) * (pb.w - pb.y);
            const float* __restrict__ srow = pd_scores + ba * NC;

            int cnt = 0, pos_g = 0;
            float best_ov = 0.0f; int best_g = 0;
            float m_align = 0.0f, m_ov = 0.0f, t_raw = 0.0f;

            for (int g = 0; g < ng; ++g) {
                if (svalid[g] == 0) break;   // mask_gt is a prefix
                float4 gb = sgt[g];
                float d0 = ax - gb.x, d1 = ay - gb.y, d2 = gb.z - ax, d3 = gb.w - ay;
                float dmin = fminf(fminf(d0, d1), fminf(d2, d3));
                bool mask = (dmin > EPSF);
                float ov = 0.0f, al = 0.0f;
                if (mask) {
                    ov = iou_xyxy(pb.x, pb.y, pb.z, pb.w, parea,
                                  gb.x, gb.y, gb.z, gb.w, sarea[g]);
                    float s = srow[slab[g]];
                    al = align_metric(s, ov);
                }
                bool pos = mask && ((w >> g) & 1ull);
                if (pos) { if (cnt == 0) pos_g = g; cnt++; }
                if (ov > best_ov) { best_ov = ov; best_g = g; }  // first max wins
                m_align = fmaxf(m_align, al);
                m_ov    = fmaxf(m_ov, ov);
                t_raw   = fmaxf(t_raw, al * ov);
            }

            int fg  = (cnt > 0) ? 1 : 0;
            int tgt = (cnt > 1) ? best_g : ((cnt == 1) ? pos_g : 0);

            labi = slab[tgt]; if (labi < 0) labi = 0;
            out_labels[ba] = (float)labi;
            ((float4*)out_bboxes)[ba] = sgt[tgt];
            out_fg[ba]  = (float)fg;
            out_tgt[ba] = (float)tgt;

            if (fg) {
                float na_ = fmaxf(m_align, EPSF);
                float no_ = fmaxf(m_ov, EPSF);
                t = (t_raw / na_) / no_;
            }
        }
    }

    plab[threadIdx.x] = labi;
    pt[threadIdx.x]   = t;
    __syncthreads();

    int cnt_rows = NA - a0; if (cnt_rows > 256) cnt_rows = 256;
    int tot4 = cnt_rows * (NC / 4);
    f4nt* __restrict__ oslab = (f4nt*)(out_scores + ((long)b * NA + a0) * NC);
    for (int i = threadIdx.x; i < tot4; i += 256) {
        int al = i / (NC / 4);
        int cg = (i - al * (NC / 4)) * 4;
        int lab = plab[al];
        float tv = pt[al];
        f4nt o;
        o.x = (cg     == lab) ? tv : 0.0f;
        o.y = (cg + 1 == lab) ? tv : 0.0f;
        o.z = (cg + 2 == lab) ? tv : 0.0f;
        o.w = (cg + 3 == lab) ? tv : 0.0f;
        __builtin_nontemporal_store(o, &oslab[i]);
    }
}

extern "C" void kernel_launch(void* const* d_in, const int* in_sizes, int n_in,
                              void* d_out, int out_size, void* d_ws, size_t ws_size,
                              hipStream_t stream) {
    const float* pd_scores = (const float*)d_in[0];
    const float* pd_bboxes = (const float*)d_in[1];
    const float* anc       = (const float*)d_in[2];
    const int*   gt_labels = (const int*)d_in[3];
    const float* gt_bboxes = (const float*)d_in[4];
    const int*   mask_gt   = (const int*)d_in[5];

    int na = in_sizes[2] / 2;            // 8400
    int bs = in_sizes[0] / (na * NC);    // 32
    int ng = in_sizes[3] / bs;           // 64

    long nBA = (long)bs * na;
    float* out        = (float*)d_out;
    float* out_labels = out;                 // bs*na
    float* out_bboxes = out + nBA;           // bs*na*4
    float* out_scores = out + nBA * 5;       // bs*na*80
    float* out_fg     = out + nBA * 85;      // bs*na
    float* out_tgt    = out + nBA * 86;      // bs*na

    unsigned long long* bits = (unsigned long long*)d_ws;

    hipMemsetAsync(d_ws, 0, nBA * sizeof(unsigned long long), stream);

    int total_bg = bs * ng;
    int nblk = (total_bg + 3) / 4;   // 4 waves (b,g) per 256-thread block
    topk_rect_kernel<<<nblk, 256, 0, stream>>>(
        pd_scores, pd_bboxes, gt_labels, gt_bboxes, mask_gt, bits, ng, total_bg);

    int bpb = (na + 255) / 256;
    assign_scores_kernel<<<bs * bpb, 256, 0, stream>>>(
        pd_scores, pd_bboxes, anc, gt_labels, gt_bboxes, mask_gt, bits,
        out_labels, out_bboxes, out_scores, out_fg, out_tgt, ng, bpb);
}

// Round 9
// 197.408 us; speedup vs baseline: 1.2340x; 1.0148x over previous
//
#include <hip/hip_runtime.h>
#include <math.h>

#define NC 80
#define TOPKK 10
#define EPSF 1e-9f
#define IOU_EPSF 1e-7f
#define NA 8400
#define NGMAX 64

typedef float f4nt __attribute__((ext_vector_type(4)));

// IoU exactly as reference: inter/(a1+a2-inter+eps)
__device__ __forceinline__ float iou_xyxy(float px0, float py0, float px1, float py1,
                                          float parea,
                                          float gx0, float gy0, float gx1, float gy1,
                                          float garea) {
    float iw = fmaxf(fminf(px1, gx1) - fmaxf(px0, gx0), 0.0f);
    float ih = fmaxf(fminf(py1, gy1) - fmaxf(py0, gy0), 0.0f);
    float inter = iw * ih;
    return inter / (parea + garea - inter + IOU_EPSF);
}

__device__ __forceinline__ float align_metric(float s, float ov) {
    float ov2 = ov * ov;
    return sqrtf(s) * (ov2 * ov2 * ov2);
}

// Top-k, rect-restricted: one 64-lane wave per (b,g); 4 waves/block; no LDS.
// Writes a COMPACT top-10 anchor-index list per (b,g) (always all 10 slots;
// -1 for invalid gts) — no global bitmask, no memset, no global atomics.
// Order/tiebreak = jax.lax.top_k (value desc, index asc) via key
// (v_bits<<32)|~idx. Zero-fill (p<10 positives) = lowest-index zero-valued
// anchors, recomputed exactly (validated in R7).
__global__ __launch_bounds__(256) void topk_rect_kernel(
    const float* __restrict__ pd_scores, const float* __restrict__ pd_bboxes,
    const int* __restrict__ gt_labels, const float* __restrict__ gt_bboxes,
    const int* __restrict__ mask_gt,
    int* __restrict__ idx_out, int ng, int total_bg)
{
    int lin = blockIdx.x * 4 + (threadIdx.x >> 6);
    if (lin >= total_bg) return;
    int b = lin / ng;
    int g = lin - b * ng;
    int lane = threadIdx.x & 63;
    int* __restrict__ slot = idx_out + (long)lin * TOPKK;

    if (mask_gt[b * ng + g] == 0) {          // invalid gt: sentinel list
        if (lane < TOPKK) slot[lane] = -1;
        return;
    }

    int lab = gt_labels[b * ng + g];
    float4 gb = ((const float4*)gt_bboxes)[b * ng + g];
    float garea = (gb.z - gb.x) * (gb.w - gb.y);
    const float* __restrict__ srow = pd_scores + ((long)b * NA) * NC + lab;
    const float4* __restrict__ pbb = (const float4*)(pd_bboxes + (long)b * NA * 4);

    // per-level candidate rectangles (superset; exact test inside loop)
    const int ls[3] = {8, 16, 32};
    const int ln[3] = {80, 40, 20};
    const int lb[3] = {0, 6400, 8000};
    int jlo[3], ilo[3], rw[3], cnt[3];
    int tot = 0;
#pragma unroll
    for (int l = 0; l < 3; ++l) {
        float s = (float)ls[l];
        int j0 = (int)floorf(gb.x / s - 0.5f) - 1; if (j0 < 0) j0 = 0;
        int j1 = (int)ceilf (gb.z / s - 0.5f) + 1; if (j1 > ln[l] - 1) j1 = ln[l] - 1;
        int i0 = (int)floorf(gb.y / s - 0.5f) - 1; if (i0 < 0) i0 = 0;
        int i1 = (int)ceilf (gb.w / s - 0.5f) + 1; if (i1 > ln[l] - 1) i1 = ln[l] - 1;
        int w = j1 - j0 + 1; if (w < 0) w = 0;
        int h = i1 - i0 + 1; if (h < 0) h = 0;
        jlo[l] = j0; ilo[l] = i0; rw[l] = w; cnt[l] = w * h; tot += cnt[l];
    }

    float lv[TOPKK]; int li[TOPKK];
#pragma unroll
    for (int j = 0; j < TOPKK; ++j) { lv[j] = -1.0f; li[j] = -1; }

    for (int t = lane; t < tot; t += 64) {   // t ascending => anchor idx ascending
        int l = 0, r = t;
        if (r >= cnt[0]) { r -= cnt[0]; l = 1; }
        if (l == 1 && r >= cnt[1]) { r -= cnt[1]; l = 2; }
        int i  = r / rw[l];
        int j  = r - i * rw[l];
        int ii = ilo[l] + i, jj = jlo[l] + j;
        int a  = lb[l] + ii * ln[l] + jj;
        float s  = (float)ls[l];
        float ax = (jj + 0.5f) * s, ay = (ii + 0.5f) * s;
        float d0 = ax - gb.x, d1 = ay - gb.y, d2 = gb.z - ax, d3 = gb.w - ay;
        float dmin = fminf(fminf(d0, d1), fminf(d2, d3));
        if (dmin > EPSF) {
            float4 pb = pbb[a];
            float parea = (pb.z - pb.x) * (pb.w - pb.y);
            float ov = iou_xyxy(pb.x, pb.y, pb.z, pb.w, parea,
                                gb.x, gb.y, gb.z, gb.w, garea);
            float sc = srow[(long)a * NC];
            float v = align_metric(sc, ov);
            if (v > 0.0f && v > lv[TOPKK - 1]) {   // positives only; sorted insert
                float nv[TOPKK]; int ni[TOPKK];
#pragma unroll
                for (int q = 0; q < TOPKK; ++q) {
                    bool keep = (lv[q] >= v);
                    bool atp  = (q == 0) ? !keep : (!keep && (lv[q - 1] >= v));
                    nv[q] = keep ? lv[q] : (atp ? v : lv[q - 1]);
                    ni[q] = keep ? li[q] : (atp ? a : li[q - 1]);
                }
#pragma unroll
                for (int q = 0; q < TOPKK; ++q) { lv[q] = nv[q]; li[q] = ni[q]; }
            }
        }
    }

    int m = 0;
    for (int it = 0; it < TOPKK; ++it) {
        unsigned long long myk = (lv[0] > 0.0f)
            ? (((unsigned long long)__float_as_uint(lv[0]) << 32)
               | (unsigned)(~(unsigned)li[0]))
            : 0ull;
        unsigned long long k = myk;
#pragma unroll
        for (int off = 32; off > 0; off >>= 1) {
            unsigned long long o = __shfl_xor(k, off, 64);
            k = (o > k) ? o : k;
        }
        if (k == 0ull) break;     // all positives drained (wave-uniform)
        if (myk == k) {           // unique owner records + pops
            slot[it] = li[0];
#pragma unroll
            for (int q = 0; q < TOPKK - 1; ++q) { lv[q] = lv[q + 1]; li[q] = li[q + 1]; }
            lv[TOPKK - 1] = -1.0f; li[TOPKK - 1] = -1;
        }
        m++;
    }

    // zero-fill slots m..9: lowest-index zero-valued anchors (recompute; skip
    // positives = already emitted). Guaranteed to find 10-m (NA-m >= need).
    if (m < TOPKK && lane == 0) {
        int p = m;
        for (int a = 0; p < TOPKK && a < NA; ++a) {
            int l  = (a < 6400) ? 0 : ((a < 8000) ? 1 : 2);
            int rr = a - lb[l];
            int ii = rr / ln[l];
            int jj = rr - ii * ln[l];
            float s  = (float)ls[l];
            float ax = (jj + 0.5f) * s, ay = (ii + 0.5f) * s;
            float d0 = ax - gb.x, d1 = ay - gb.y, d2 = gb.z - ax, d3 = gb.w - ay;
            float dmin = fminf(fminf(d0, d1), fminf(d2, d3));
            bool positive = false;
            if (dmin > EPSF) {
                float4 pb = pbb[a];
                float parea = (pb.z - pb.x) * (pb.w - pb.y);
                float ov = iou_xyxy(pb.x, pb.y, pb.z, pb.w, parea,
                                    gb.x, gb.y, gb.z, gb.w, garea);
                float sc = srow[(long)a * NC];
                positive = (align_metric(sc, ov) > 0.0f);
            }
            if (!positive) slot[p++] = a;   // zero-valued: in reference topk
        }
    }
}

// Fused assign + scores. Rebuilds the per-anchor g-bitmask in LDS from the
// compact index lists (640 entries/batch), then: w==0 fast path or g-loop.
__global__ __launch_bounds__(256) void assign_scores_kernel(
    const float* __restrict__ pd_scores, const float* __restrict__ pd_bboxes,
    const float* __restrict__ anc, const int* __restrict__ gt_labels,
    const float* __restrict__ gt_bboxes, const int* __restrict__ mask_gt,
    const int* __restrict__ idx_in,
    float* __restrict__ out_labels, float* __restrict__ out_bboxes,
    float* __restrict__ out_scores, float* __restrict__ out_fg,
    float* __restrict__ out_tgt, int ng, int blocksPerB)
{
    __shared__ float4 sgt[NGMAX];
    __shared__ float  sarea[NGMAX];
    __shared__ int    slab[NGMAX];
    __shared__ int    svalid[NGMAX];
    __shared__ unsigned long long smask[256];
    __shared__ int    plab[256];
    __shared__ float  pt[256];

    int b  = blockIdx.x / blocksPerB;
    int a0 = (blockIdx.x - b * blocksPerB) * 256;
    int a  = a0 + threadIdx.x;

    smask[threadIdx.x] = 0ull;
    for (int g = threadIdx.x; g < ng; g += 256) {
        float4 gb = ((const float4*)gt_bboxes)[b * ng + g];
        sgt[g] = gb;
        sarea[g] = (gb.z - gb.x) * (gb.w - gb.y);
        slab[g] = gt_labels[b * ng + g];
        svalid[g] = mask_gt[b * ng + g];
    }
    __syncthreads();

    // build bitmask for this block's anchors from the compact lists
    {
        int nent = ng * TOPKK;                        // 640
        const int* lst = idx_in + (long)b * nent;
        for (int i = threadIdx.x; i < nent; i += 256) {
            int aa = lst[i];
            unsigned off = (unsigned)(aa - a0);
            if (aa >= 0 && off < 256u) {
                atomicOr(&smask[off], 1ull << (i / TOPKK));   // g = i/10
            }
        }
    }
    __syncthreads();

    bool alive = (a < NA);
    int labi0 = slab[0] < 0 ? 0 : slab[0];
    int labi = labi0; float t = 0.0f;

    if (alive) {
        long ba = (long)b * NA + a;
        unsigned long long w = smask[threadIdx.x];
        if (w == 0ull) {
            // fg=0, tgt=argmax(zeros)=0: defaults, exact per reference algebra
            out_labels[ba] = (float)labi0;
            ((float4*)out_bboxes)[ba] = sgt[0];
            out_fg[ba]  = 0.0f;
            out_tgt[ba] = 0.0f;
        } else {
            float ax = anc[a * 2 + 0];
            float ay = anc[a * 2 + 1];
            float4 pb = ((const float4*)pd_bboxes)[ba];
            float parea = (pb.z - pb.x) * (pb.w - pb.y);
            const float* __restrict__ srow = pd_scores + ba * NC;

            int cnt = 0, pos_g = 0;
            float best_ov = 0.0f; int best_g = 0;
            float m_align = 0.0f, m_ov = 0.0f, t_raw = 0.0f;

            for (int g = 0; g < ng; ++g) {
                if (svalid[g] == 0) break;   // mask_gt is a prefix
                float4 gb = sgt[g];
                float d0 = ax - gb.x, d1 = ay - gb.y, d2 = gb.z - ax, d3 = gb.w - ay;
                float dmin = fminf(fminf(d0, d1), fminf(d2, d3));
                bool mask = (dmin > EPSF);
                float ov = 0.0f, al = 0.0f;
                if (mask) {
                    ov = iou_xyxy(pb.x, pb.y, pb.z, pb.w, parea,
                                  gb.x, gb.y, gb.z, gb.w, sarea[g]);
                    float s = srow[slab[g]];
                    al = align_metric(s, ov);
                }
                bool pos = mask && ((w >> g) & 1ull);
                if (pos) { if (cnt == 0) pos_g = g; cnt++; }
                if (ov > best_ov) { best_ov = ov; best_g = g; }  // first max wins
                m_align = fmaxf(m_align, al);
                m_ov    = fmaxf(m_ov, ov);
                t_raw   = fmaxf(t_raw, al * ov);
            }

            int fg  = (cnt > 0) ? 1 : 0;
            int tgt = (cnt > 1) ? best_g : ((cnt == 1) ? pos_g : 0);

            labi = slab[tgt]; if (labi < 0) labi = 0;
            out_labels[ba] = (float)labi;
            ((float4*)out_bboxes)[ba] = sgt[tgt];
            out_fg[ba]  = (float)fg;
            out_tgt[ba] = (float)tgt;

            if (fg) {
                float na_ = fmaxf(m_align, EPSF);
                float no_ = fmaxf(m_ov, EPSF);
                t = (t_raw / na_) / no_;
            }
        }
    }

    plab[threadIdx.x] = labi;
    pt[threadIdx.x]   = t;
    __syncthreads();

    int cnt_rows = NA - a0; if (cnt_rows > 256) cnt_rows = 256;
    int tot4 = cnt_rows * (NC / 4);
    f4nt* __restrict__ oslab = (f4nt*)(out_scores + ((long)b * NA + a0) * NC);
    for (int i = threadIdx.x; i < tot4; i += 256) {
        int al = i / (NC / 4);
        int cg = (i - al * (NC / 4)) * 4;
        int lab = plab[al];
        float tv = pt[al];
        f4nt o;
        o.x = (cg     == lab) ? tv : 0.0f;
        o.y = (cg + 1 == lab) ? tv : 0.0f;
        o.z = (cg + 2 == lab) ? tv : 0.0f;
        o.w = (cg + 3 == lab) ? tv : 0.0f;
        __builtin_nontemporal_store(o, &oslab[i]);
    }
}

extern "C" void kernel_launch(void* const* d_in, const int* in_sizes, int n_in,
                              void* d_out, int out_size, void* d_ws, size_t ws_size,
                              hipStream_t stream) {
    const float* pd_scores = (const float*)d_in[0];
    const float* pd_bboxes = (const float*)d_in[1];
    const float* anc       = (const float*)d_in[2];
    const int*   gt_labels = (const int*)d_in[3];
    const float* gt_bboxes = (const float*)d_in[4];
    const int*   mask_gt   = (const int*)d_in[5];

    int na = in_sizes[2] / 2;            // 8400
    int bs = in_sizes[0] / (na * NC);    // 32
    int ng = in_sizes[3] / bs;           // 64

    long nBA = (long)bs * na;
    float* out        = (float*)d_out;
    float* out_labels = out;                 // bs*na
    float* out_bboxes = out + nBA;           // bs*na*4
    float* out_scores = out + nBA * 5;       // bs*na*80
    float* out_fg     = out + nBA * 85;      // bs*na
    float* out_tgt    = out + nBA * 86;      // bs*na

    int* idx = (int*)d_ws;                   // bs*ng*10 ints ≈ 82 KB, no memset

    int total_bg = bs * ng;
    int nblk = (total_bg + 3) / 4;   // 4 waves (b,g) per 256-thread block
    topk_rect_kernel<<<nblk, 256, 0, stream>>>(
        pd_scores, pd_bboxes, gt_labels, gt_bboxes, mask_gt, idx, ng, total_bg);

    int bpb = (na + 255) / 256;
    assign_scores_kernel<<<bs * bpb, 256, 0, stream>>>(
        pd_scores, pd_bboxes, anc, gt_labels, gt_bboxes, mask_gt, idx,
        out_labels, out_bboxes, out_scores, out_fg, out_tgt, ng, bpb);
}